// Round 4
// baseline (184.535 us; speedup 1.0000x reference)
//
#include <hip/hip_runtime.h>
#include <math.h>

#define N_NODES   50000
#define N_EDGES   400000
#define NCH       16
#define CAP       48          // per-node edge capacity; P(deg>48 | lambda=8) ~ 1e-17
#define EBUF_PAD  16          // slack slots so in-loop record prefetch never reads OOB
#define NSTRIPE   8
#define TPB       256
#define NBN       ((N_NODES + TPB - 1) / TPB)   // 196
#define NB_EDGES  ((N_EDGES + TPB - 1) / TPB)   // 1563
#define NB_MAIN   ((N_NODES / 2 * 64) / TPB)    // 6250: 2 nodes per wave

// ======================= FAST PATH (bucketed, 3 dispatches) =======================

// K1: per-edge geometry + direct bucket write of a SLIM 8B record {e, d}.
__global__ void build_kernel(const float* __restrict__ pos,
                             const int* __restrict__ src,
                             const int* __restrict__ dst,
                             float* __restrict__ dists,
                             int* __restrict__ cnt,
                             int2* __restrict__ ebuf) {
    int e = blockIdx.x * TPB + threadIdx.x;
    if (e >= N_EDGES) return;
    int s = src[e];
    int d = dst[e];
    float rx = pos[3 * s + 0] - pos[3 * d + 0];
    float ry = pos[3 * s + 1] - pos[3 * d + 1];
    float rz = pos[3 * s + 2] - pos[3 * d + 2];
    float dist = sqrtf(rx * rx + ry * ry + rz * rz);
    dists[e] = dist;
    int slot = atomicAdd(&cnt[s], 1);
    if (slot < CAP) {
        ebuf[s * CAP + slot] = make_int2(e, d);
    }
}

// ---- shared per-edge math (verified against reference) ----
__device__ __forceinline__ void edge_math(
    float ux, float uy, float uz, float R,
    float A0, const float A1[3], const float A2[9],
    float& acc0, float acc1[3], float acc2[9])
{
    float u[3] = {ux, uy, uz};
    float d1 = A1[0] * ux + A1[1] * uy + A1[2] * uz;   // A1.u
    float tA = A2[0] + A2[4] + A2[8];                   // tr(A2)
    float v0 = A2[0] * ux + A2[1] * uy + A2[2] * uz;    // A2 u
    float v1 = A2[3] * ux + A2[4] * uy + A2[5] * uz;
    float v2 = A2[6] * ux + A2[7] * uy + A2[8] * uz;
    float w0 = A2[0] * ux + A2[3] * uy + A2[6] * uz;    // A2^T u
    float w1 = A2[1] * ux + A2[4] * uy + A2[7] * uz;
    float w2 = A2[2] * ux + A2[5] * uy + A2[8] * uz;
    float q = ux * v0 + uy * v1 + uz * v2;              // u^T A2 u

    acc0 += R * (2.0f * A0 + d1 + 2.0f * tA + 2.0f * q);

    float svw[3] = {v0 + w0, v1 + w1, v2 + w2};
    float a0t = A0 + tA;
#pragma unroll
    for (int mm = 0; mm < 3; ++mm) {
        acc1[mm] += R * (A0 * u[mm] + 2.0f * A1[mm] + 2.0f * d1 * u[mm]
                         + svw[mm] + tA * u[mm]);
#pragma unroll
        for (int nn = 0; nn < 3; ++nn) {
            acc2[3 * mm + nn] += R * (a0t * u[mm] * u[nn] + A1[mm] * u[nn]
                                      + 2.0f * A2[3 * mm + nn]
                                      + 2.0f * svw[mm] * u[nn]);
        }
    }
}

// ---- unconditional full prefetch set for one edge: pos[d], h rows, radial ----
// d and e MUST already be clamped to valid ranges by the caller (node 0 / edge 0
// for invalid slots -> permanently L2-hot lines, no extra HBM traffic).
__device__ __forceinline__ void load_hsetp(
    const float* __restrict__ h0, const float* __restrict__ h1,
    const float* __restrict__ h2, const float* __restrict__ pos,
    const float* __restrict__ dists,
    int d, int e, int k,
    float& P0, float& P1, float& P2,
    float& A0, float A1[3], float A2[9], float& r, float& nf)
{
    P0 = pos[3 * d + 0];
    P1 = pos[3 * d + 1];
    P2 = pos[3 * d + 2];
    A0 = h0[d * NCH + k];
    const float* p1 = h1 + ((size_t)d * NCH + k) * 3;
    A1[0] = p1[0]; A1[1] = p1[1]; A1[2] = p1[2];
    const float* p2 = h2 + ((size_t)d * NCH + k) * 9;
#pragma unroll
    for (int q2 = 0; q2 < 9; ++q2) A2[q2] = p2[q2];
    // radial with the reference's faithful [K,E]->[E,K] reshape
    unsigned f = (unsigned)e * NCH + (unsigned)k;
    unsigned n_idx = f / (unsigned)N_EDGES;
    unsigned e_idx = f - n_idx * (unsigned)N_EDGES;
    r = dists[e_idx];
    nf = (float)(n_idx + 1);
}

// ---- fallback-path helpers (kept as before) ----
__device__ __forceinline__ void load_hset(
    const float* __restrict__ h0, const float* __restrict__ h1,
    const float* __restrict__ h2, const float* __restrict__ dists,
    int d, int e, int k,
    float& A0, float A1[3], float A2[9], float& r, float& nf)
{
    A0 = h0[d * NCH + k];
    const float* p1 = h1 + ((size_t)d * NCH + k) * 3;
    A1[0] = p1[0]; A1[1] = p1[1]; A1[2] = p1[2];
    const float* p2 = h2 + ((size_t)d * NCH + k) * 9;
#pragma unroll
    for (int q2 = 0; q2 < 9; ++q2) A2[q2] = p2[q2];
    unsigned f = (unsigned)e * NCH + (unsigned)k;
    unsigned n_idx = f / (unsigned)N_EDGES;
    unsigned e_idx = f - n_idx * (unsigned)N_EDGES;
    r = dists[e_idx];
    nf = (float)(n_idx + 1);
}

__device__ __forceinline__ float radial_R(float nf, float r) {
    return 0.44721359549995794f * __sinf(nf * 0.3141592653589793f * r) / r;
}

// K2: main — TWO nodes per wave (half = lane>>5), j in {0,1}, k = lane&15.
// Depth-1 software pipeline: while edge c is computed, edge c+2's full
// load-set (pos/h/dists) is already in flight via select-clamped indices.
__global__ void node_wave_fast(const float* __restrict__ h0,
                               const float* __restrict__ h1,
                               const float* __restrict__ h2,
                               const float* __restrict__ pos,
                               const int* __restrict__ cnt,
                               const int2* __restrict__ ebuf,
                               const float* __restrict__ dists,
                               float* __restrict__ out0,
                               float* __restrict__ out1,
                               float* __restrict__ out2) {
    int gid = blockIdx.x * TPB + threadIdx.x;
    int lane = threadIdx.x & 63;
    int half = lane >> 5;          // which node of the pair
    int j = (lane >> 4) & 1;       // edge-slot parity within node
    int k = lane & 15;             // channel
    int node = (gid >> 6) * 2 + half;
    if (node >= N_NODES) return;
    int base = node * CAP;

    // node-entry: cnt + own position + first record, all independent
    int m = cnt[node];
    float ps0 = pos[3 * node + 0];
    float ps1 = pos[3 * node + 1];
    float ps2 = pos[3 * node + 2];
    int c = j;
    int2 pk = ebuf[base + c];          // slot 0/1: always within the row
    if (m > CAP) m = CAP;

    // prologue: issue current edge's full set (clamped)
    bool v0 = (c < m);
    int dc = v0 ? pk.y : 0;
    int ec = v0 ? pk.x : 0;
    float pd0, pd1, pd2, A0, A1[3], A2[9], rr, nf;
    load_hsetp(h0, h1, h2, pos, dists, dc, ec, k,
               pd0, pd1, pd2, A0, A1, A2, rr, nf);

    float acc0 = 0.0f;
    float acc1[3] = {0.0f, 0.0f, 0.0f};
    float acc2[9] = {0.0f, 0.0f, 0.0f, 0.0f, 0.0f, 0.0f, 0.0f, 0.0f, 0.0f};

    while (c < m) {
        int cn = c + 2;
        // next record (padded buffer: base+cn always readable; clamped before use)
        int2 pk1 = ebuf[base + cn];
        bool vn = (cn < m);
        int dn = vn ? pk1.y : 0;
        int en = vn ? pk1.x : 0;
        // issue next edge's full set NOW; latency hides under current compute
        float qd0, qd1, qd2, B0, B1[3], B2[9], sr, snf;
        load_hsetp(h0, h1, h2, pos, dists, dn, en, k,
                   qd0, qd1, qd2, B0, B1, B2, sr, snf);

        // ---- compute current edge (always valid: loop condition is per-lane) ----
        float rcp_r = __builtin_amdgcn_rcpf(rr);
        float R = 0.44721359549995794f *
                  __sinf(nf * 0.3141592653589793f * rr) * rcp_r;
        float rx = ps0 - pd0;
        float ry = ps1 - pd1;
        float rz = ps2 - pd2;
        float s2 = rx * rx + ry * ry + rz * rz;
        float inv = __builtin_amdgcn_rsqf(s2);
        edge_math(rx * inv, ry * inv, rz * inv, R, A0, A1, A2, acc0, acc1, acc2);

        // rotate pipeline
        pd0 = qd0; pd1 = qd1; pd2 = qd2;
        A0 = B0;
        A1[0] = B1[0]; A1[1] = B1[1]; A1[2] = B1[2];
#pragma unroll
        for (int q2 = 0; q2 < 9; ++q2) A2[q2] = B2[q2];
        rr = sr; nf = snf;
        c = cn;
    }

    // reduce over j (xor 16 stays within each 32-lane half -> same node)
    acc0 += __shfl_xor(acc0, 16, 64);
#pragma unroll
    for (int mm = 0; mm < 3; ++mm) acc1[mm] += __shfl_xor(acc1[mm], 16, 64);
#pragma unroll
    for (int mm = 0; mm < 9; ++mm) acc2[mm] += __shfl_xor(acc2[mm], 16, 64);

    if (j == 0) {
        int t = node * NCH + k;
        out0[t] = acc0;
        float* o1p = out1 + (size_t)t * 3;
#pragma unroll
        for (int mm = 0; mm < 3; ++mm) o1p[mm] = acc1[mm];
        float* o2p = out2 + (size_t)t * 9;
#pragma unroll
        for (int mm = 0; mm < 9; ++mm) o2p[mm] = acc2[mm];
    }
}

// ======================= FALLBACK (R8 pipeline, small ws) =======================

__global__ void fb_geom_hist(const float* __restrict__ pos,
                             const int* __restrict__ src,
                             const int* __restrict__ dst,
                             float* __restrict__ dists,
                             int* __restrict__ cnt8,
                             int* __restrict__ rankArr) {
    int e = blockIdx.x * TPB + threadIdx.x;
    if (e >= N_EDGES) return;
    int stripe = blockIdx.x & (NSTRIPE - 1);
    int s = src[e];
    int d = dst[e];
    float rx = pos[3 * s + 0] - pos[3 * d + 0];
    float ry = pos[3 * s + 1] - pos[3 * d + 1];
    float rz = pos[3 * s + 2] - pos[3 * d + 2];
    dists[e] = sqrtf(rx * rx + ry * ry + rz * rz);
    rankArr[e] = atomicAdd(&cnt8[stripe * N_NODES + s], 1);
}

__global__ void fb_scan(const int* __restrict__ cnt8,
                        int* __restrict__ incl,
                        int* __restrict__ bsum) {
    __shared__ int sh[TPB];
    int tid = threadIdx.x;
    int i = blockIdx.x * TPB + tid;
    int tot = 0;
    if (i < N_NODES) {
#pragma unroll
        for (int c = 0; c < NSTRIPE; ++c) tot += cnt8[c * N_NODES + i];
    }
    sh[tid] = tot;
    __syncthreads();
    for (int s = 1; s < TPB; s <<= 1) {
        int x = 0;
        if (tid >= s) x = sh[tid - s];
        __syncthreads();
        if (tid >= s) sh[tid] += x;
        __syncthreads();
    }
    if (i < N_NODES) incl[i] = sh[tid];
    if (tid == TPB - 1) bsum[blockIdx.x] = sh[TPB - 1];
}

__global__ void fb_final(const int* __restrict__ cnt8,
                         const int* __restrict__ incl,
                         const int* __restrict__ bsum,
                         int* __restrict__ offsets,
                         int* __restrict__ copyBase) {
    __shared__ int sh[TPB];
    int tid = threadIdx.x;
    int b = blockIdx.x;
    sh[tid] = (tid < b) ? bsum[tid] : 0;
    __syncthreads();
    for (int s = 128; s > 0; s >>= 1) {
        if (tid < s) sh[tid] += sh[tid + s];
        __syncthreads();
    }
    int base = sh[0];
    int i = b * TPB + tid;
    if (i < N_NODES) {
        int cv[NSTRIPE];
        int tot = 0;
#pragma unroll
        for (int c = 0; c < NSTRIPE; ++c) { cv[c] = cnt8[c * N_NODES + i]; tot += cv[c]; }
        int off = base + incl[i] - tot;
        offsets[i] = off;
        int run = off;
#pragma unroll
        for (int c = 0; c < NSTRIPE; ++c) { copyBase[c * N_NODES + i] = run; run += cv[c]; }
    }
    if (b == 0 && tid == 0) offsets[N_NODES] = N_EDGES;
}

__global__ void fb_fill(const int* __restrict__ src,
                        const int* __restrict__ dst,
                        const float* __restrict__ pos,
                        const float* __restrict__ dists,
                        const int* __restrict__ copyBase,
                        const int* __restrict__ rankArr,
                        float4* __restrict__ edata,
                        int* __restrict__ csr) {
    int e = blockIdx.x * TPB + threadIdx.x;
    if (e >= N_EDGES) return;
    int stripe = blockIdx.x & (NSTRIPE - 1);
    int s = src[e];
    int d = dst[e];
    float rx = pos[3 * s + 0] - pos[3 * d + 0];
    float ry = pos[3 * s + 1] - pos[3 * d + 1];
    float rz = pos[3 * s + 2] - pos[3 * d + 2];
    float inv = 1.0f / dists[e];
    int slot = copyBase[stripe * N_NODES + s] + rankArr[e];
    float4 ed;
    ed.x = rx * inv;
    ed.y = ry * inv;
    ed.z = rz * inv;
    ed.w = __int_as_float(d);
    edata[slot] = ed;
    csr[slot] = e;
}

__global__ void fb_main(const float* __restrict__ h0,
                        const float* __restrict__ h1,
                        const float* __restrict__ h2,
                        const int* __restrict__ offsets,
                        const float4* __restrict__ edata,
                        const int* __restrict__ csr,
                        const float* __restrict__ dists,
                        float* __restrict__ out0,
                        float* __restrict__ out1,
                        float* __restrict__ out2) {
    int gid = blockIdx.x * TPB + threadIdx.x;
    int node = gid >> 6;
    if (node >= N_NODES) return;
    int lane = threadIdx.x & 63;
    int k = lane & 15;
    int j = lane >> 4;
    int beg = offsets[node];
    int end = offsets[node + 1];

    float acc0 = 0.0f;
    float acc1[3] = {0.0f, 0.0f, 0.0f};
    float acc2[9] = {0.0f, 0.0f, 0.0f, 0.0f, 0.0f, 0.0f, 0.0f, 0.0f, 0.0f};

    int i = beg + j;
    float4 ed;
    int e = 0;
    if (i < end) { ed = edata[i]; e = csr[i]; }
    while (i < end) {
        int inext = i + 4;
        float4 edn = ed;
        int en = e;
        if (inext < end) { edn = edata[inext]; en = csr[inext]; }

        int d = __float_as_int(ed.w);
        float a0, a1[3], a2[9], r, nf;
        load_hset(h0, h1, h2, dists, d, e, k, a0, a1, a2, r, nf);
        float R = radial_R(nf, r);
        edge_math(ed.x, ed.y, ed.z, R, a0, a1, a2, acc0, acc1, acc2);

        ed = edn;
        e = en;
        i = inext;
    }

    acc0 += __shfl_xor(acc0, 16, 64);
    acc0 += __shfl_xor(acc0, 32, 64);
#pragma unroll
    for (int mm = 0; mm < 3; ++mm) {
        acc1[mm] += __shfl_xor(acc1[mm], 16, 64);
        acc1[mm] += __shfl_xor(acc1[mm], 32, 64);
    }
#pragma unroll
    for (int mm = 0; mm < 9; ++mm) {
        acc2[mm] += __shfl_xor(acc2[mm], 16, 64);
        acc2[mm] += __shfl_xor(acc2[mm], 32, 64);
    }

    if (j == 0) {
        int t = node * NCH + k;
        out0[t] = acc0;
        float* o1p = out1 + (size_t)t * 3;
#pragma unroll
        for (int mm = 0; mm < 3; ++mm) o1p[mm] = acc1[mm];
        float* o2p = out2 + (size_t)t * 9;
#pragma unroll
        for (int mm = 0; mm < 9; ++mm) o2p[mm] = acc2[mm];
    }
}

// ======================= host =======================

extern "C" void kernel_launch(void* const* d_in, const int* in_sizes, int n_in,
                              void* d_out, int out_size, void* d_ws, size_t ws_size,
                              hipStream_t stream) {
    const float* h0  = (const float*)d_in[0];
    const float* h1  = (const float*)d_in[1];
    const float* h2  = (const float*)d_in[2];
    const float* pos = (const float*)d_in[3];
    // d_in[4] = channel_weights: dead in the reference dataflow
    const int* edge_index = (const int*)d_in[5];
    const int* src = edge_index;
    const int* dst = edge_index + N_EDGES;

    float* out = (float*)d_out;
    float* out0 = out;                                  // [N,16]
    float* out1 = out + (size_t)N_NODES * NCH;          // [N,16,3]
    float* out2 = out + (size_t)N_NODES * NCH * 4;      // [N,16,9]

    // fast-path workspace: ebuf[N*CAP + pad] int2 + dists[E] + cnt[N]
    size_t need = ((size_t)N_NODES * CAP + EBUF_PAD) * 8
                + (size_t)N_EDGES * 4 + (size_t)N_NODES * 4;

    if (ws_size >= need) {
        int2* ebuf   = (int2*)d_ws;                                      // [N*CAP+pad]
        float* dists = (float*)(ebuf + (size_t)N_NODES * CAP + EBUF_PAD);
        int* cnt     = (int*)(dists + N_EDGES);

        hipMemsetAsync(cnt, 0, N_NODES * sizeof(int), stream);
        build_kernel<<<NB_EDGES, TPB, 0, stream>>>(pos, src, dst, dists, cnt, ebuf);
        node_wave_fast<<<NB_MAIN, TPB, 0, stream>>>(
            h0, h1, h2, pos, cnt, ebuf, dists, out0, out1, out2);
    } else {
        // R8 pipeline (~15 MB ws)
        float4* edata   = (float4*)d_ws;                            // [E]
        float*  dists   = (float*)(edata + N_EDGES);                // [E]
        int* cnt8       = (int*)(dists + N_EDGES);                  // [8][N]
        int* rankArr    = cnt8 + NSTRIPE * N_NODES;                 // [E]
        int* incl       = rankArr + N_EDGES;                        // [N]
        int* bsum       = incl + N_NODES;                           // [NBN]
        int* offsets    = bsum + 256;                               // [N+1]
        int* copyBase   = offsets + N_NODES + 1;                    // [8][N]
        int* csr        = copyBase + NSTRIPE * N_NODES;             // [E]

        hipMemsetAsync(cnt8, 0, NSTRIPE * N_NODES * sizeof(int), stream);
        fb_geom_hist<<<NB_EDGES, TPB, 0, stream>>>(pos, src, dst, dists, cnt8, rankArr);
        fb_scan<<<NBN, TPB, 0, stream>>>(cnt8, incl, bsum);
        fb_final<<<NBN, TPB, 0, stream>>>(cnt8, incl, bsum, offsets, copyBase);
        fb_fill<<<NB_EDGES, TPB, 0, stream>>>(src, dst, pos, dists, copyBase, rankArr, edata, csr);
        fb_main<<<(N_NODES * 64 + TPB - 1) / TPB, TPB, 0, stream>>>(
            h0, h1, h2, offsets, edata, csr, dists, out0, out1, out2);
    }
}